// Round 2
// 285.350 us; speedup vs baseline: 1.0039x; 1.0039x over previous
//
#include <hip/hip_runtime.h>

// T1: (P=4, B=8192, C=128, 3, 3) fp32
// T2: (1, B, C, 3, 3) fp32 (broadcast over P)
// out[p,b,c,i,j] = sum_k T1[p,b,c,i,k] * T2[0,b,c,k,j]
//
// R4: R3 (global_load_lds variant) killed the container twice; this round
// keeps the same coalescing/occupancy redesign but stages via registers +
// ds_write (constructs proven in the 286us R2 run):
//   - one 3x3 cell per thread, 256 cells/block, 4096 blocks
//   - ALL global accesses lane-contiguous 16B/lane (global_load_dwordx4)
//   - reg->LDS staging; compute reads own 9-float slice (stride-9 floats:
//     odd stride -> 64 lanes hit 2/bank = conflict-free)
//   - result stashed in own slice of the dead B buffer (no extra barrier)
//   - next-p A loads ISSUED before the store phase, LDS-WRITTEN after it
//     (T14 issue-early/write-late: HBM latency hides under the stores)
//   - LDS 18KB -> 8 blocks/CU = 32 waves/CU occupancy cap

typedef float floatx4 __attribute__((ext_vector_type(4)));

__global__ __launch_bounds__(256) void tc33_kernel(const float* __restrict__ T1,
                                                   const float* __restrict__ T2,
                                                   float* __restrict__ out) {
    __shared__ float sA[2304];   // 9216 B: A chunk (256 cells x 9 floats)
    __shared__ float sB[2304];   // 9216 B: B chunk, then reused as out staging
    const long long PER_P = 9LL * 8192 * 128;            // floats per p-slice
    const int tid = threadIdx.x;
    const long long base = (long long)blockIdx.x * 2304; // float offset of chunk

    floatx4* SA4 = reinterpret_cast<floatx4*>(sA);
    floatx4* SB4 = reinterpret_cast<floatx4*>(sB);

    // Prologue: coalesced load of B chunk and A(p=0) chunk (576 float4 each).
    {
        const floatx4* Bg = reinterpret_cast<const floatx4*>(T2 + base);
        const floatx4* Ag = reinterpret_cast<const floatx4*>(T1 + base);
        floatx4 rb0 = Bg[tid], rb1 = Bg[tid + 256];
        floatx4 ra0 = Ag[tid], ra1 = Ag[tid + 256];
        SB4[tid] = rb0; SB4[tid + 256] = rb1;
        SA4[tid] = ra0; SA4[tid + 256] = ra1;
        if (tid < 64) {
            floatx4 rb2 = Bg[tid + 512];
            floatx4 ra2 = Ag[tid + 512];
            SB4[tid + 512] = rb2;
            SA4[tid + 512] = ra2;
        }
    }
    __syncthreads();

    // Each thread's B matrix -> registers (own slice; sB dead afterwards).
    float b[9];
    #pragma unroll
    for (int i = 0; i < 9; ++i) b[i] = sB[tid * 9 + i];

    #pragma unroll
    for (int p = 0; p < 4; ++p) {
        float a[9];
        #pragma unroll
        for (int i = 0; i < 9; ++i) a[i] = sA[tid * 9 + i];

        float o[9];
        #pragma unroll
        for (int i = 0; i < 3; ++i) {
            #pragma unroll
            for (int j = 0; j < 3; ++j) {
                float s = a[i * 3 + 0] * b[0 * 3 + j];
                s = fmaf(a[i * 3 + 1], b[1 * 3 + j], s);
                s = fmaf(a[i * 3 + 2], b[2 * 3 + j], s);
                o[i * 3 + j] = s;
            }
        }

        // Stash result in OWN slice of sB (b already in regs; no cross-thread
        // reader of this slice until the post-barrier store phase).
        #pragma unroll
        for (int i = 0; i < 9; ++i) sB[tid * 9 + i] = o[i];

        __syncthreads();  // S1: all sA reads + own-slice sB writes done

        // Issue next-p A loads EARLY (coalesced); LDS-write them LATE so the
        // HBM latency hides under the store phase below.
        floatx4 na0, na1, na2;
        if (p < 3) {
            const floatx4* An =
                reinterpret_cast<const floatx4*>(T1 + (p + 1) * PER_P + base);
            na0 = An[tid];
            na1 = An[tid + 256];
            if (tid < 64) na2 = An[tid + 512];
        }

        // Coalesced nontemporal store of the chunk from sB.
        {
            floatx4* O4 = reinterpret_cast<floatx4*>(out + p * PER_P + base);
            const floatx4* S4 = reinterpret_cast<const floatx4*>(sB);
            __builtin_nontemporal_store(S4[tid      ], &O4[tid      ]);
            __builtin_nontemporal_store(S4[tid + 256], &O4[tid + 256]);
            if (tid < 64)
                __builtin_nontemporal_store(S4[tid + 512], &O4[tid + 512]);
        }

        // Write-late: commit the prefetched A chunk into sA.
        if (p < 3) {
            SA4[tid      ] = na0;
            SA4[tid + 256] = na1;
            if (tid < 64) SA4[tid + 512] = na2;
        }

        __syncthreads();  // S2: sA writes + sB store-reads done
    }
}

extern "C" void kernel_launch(void* const* d_in, const int* in_sizes, int n_in,
                              void* d_out, int out_size, void* d_ws, size_t ws_size,
                              hipStream_t stream) {
    const float* T1 = (const float*)d_in[0];
    const float* T2 = (const float*)d_in[1];
    float* out = (float*)d_out;

    // B*C = 1,048,576 cells; 256 cells/block -> 4096 blocks, 256 threads each.
    const int threads = 256;
    const int blocks = (8192 * 128) / 256;  // 4096
    tc33_kernel<<<blocks, threads, 0, stream>>>(T1, T2, out);
}

// Round 3
// 283.020 us; speedup vs baseline: 1.0121x; 1.0082x over previous
//
#include <hip/hip_runtime.h>

// T1: (P=4, B=8192, C=128, 3, 3) fp32
// T2: (1, B, C, 3, 3) fp32 (broadcast over P)
// out[p,b,c,i,j] = sum_k T1[p,b,c,i,k] * T2[0,b,c,k,j]
//
// R5: R2 (strided loads, 4 blk/CU) and R4 (coalesced loads, 67% occupancy)
// both pinned at ~105us with VALUBusy ~3% and HBM ~29% -> the shared
// bottleneck is the per-iteration __syncthreads after the NT store phase:
// hipcc lowers it as s_waitcnt vmcnt(0) + s_barrier, draining all NT stores
// to memory 4x per block with all blocks in lockstep.
// This version has ZERO __syncthreads:
//   - output transpose staged in WAVE-PRIVATE LDS slices (576 floats/wave);
//     DS ops from one wave execute in order -> wave-synchronous, barrier-free
//     (wave_barrier() pins compiler ordering, zero HW cost)
//   - strided direct loads (proven irrelevant vs coalesced in R2 vs R4;
//     inputs L2/L3-resident), next-p A loads issued early for overlap
//   - NT stores fire-and-forget: no vmcnt(0) until kernel end
//   - LDS 9216 B/block -> occupancy capped only by waves (8 blk/CU)

typedef float floatx4 __attribute__((ext_vector_type(4)));

__global__ __launch_bounds__(256) void tc33_kernel(const float* __restrict__ T1,
                                                   const float* __restrict__ T2,
                                                   float* __restrict__ out) {
    __shared__ float so[2304];                 // 4 wave-private 576-float slices
    const long long PER_P = 9LL * 8192 * 128;  // floats per p-slice
    const int tid = threadIdx.x;
    const int w = tid >> 6;                    // wave id within block
    const int l = tid & 63;                    // lane
    const long long cell  = (long long)blockIdx.x * 256 + tid;        // cell id
    const long long cbase = cell * 9;                                 // float off
    const long long wbase = (long long)blockIdx.x * 2304 + (long long)w * 576;

    float* slice = so + w * 576;
    floatx4* S4  = reinterpret_cast<floatx4*>(slice);

    // ---- B matrix: 9 strided floats (4B-aligned dwordx4 is fine; proven R2) --
    float b[9];
    {
        floatx4 v0 = *reinterpret_cast<const floatx4*>(T2 + cbase);
        floatx4 v1 = *reinterpret_cast<const floatx4*>(T2 + cbase + 4);
        float   v8 = T2[cbase + 8];
        b[0] = v0.x; b[1] = v0.y; b[2] = v0.z; b[3] = v0.w;
        b[4] = v1.x; b[5] = v1.y; b[6] = v1.z; b[7] = v1.w;
        b[8] = v8;
    }

    // ---- prime A(p=0) ----
    floatx4 ra0 = *reinterpret_cast<const floatx4*>(T1 + cbase);
    floatx4 ra1 = *reinterpret_cast<const floatx4*>(T1 + cbase + 4);
    float   ra8 = T1[cbase + 8];

    #pragma unroll
    for (int p = 0; p < 4; ++p) {
        float a[9];
        a[0] = ra0.x; a[1] = ra0.y; a[2] = ra0.z; a[3] = ra0.w;
        a[4] = ra1.x; a[5] = ra1.y; a[6] = ra1.z; a[7] = ra1.w;
        a[8] = ra8;

        // Issue next-p loads NOW; consumed at the top of the next iteration,
        // so their latency hides under compute + staging + stores of this p.
        if (p < 3) {
            const float* An = T1 + (long long)(p + 1) * PER_P + cbase;
            ra0 = *reinterpret_cast<const floatx4*>(An);
            ra1 = *reinterpret_cast<const floatx4*>(An + 4);
            ra8 = An[8];
        }

        float o[9];
        #pragma unroll
        for (int i = 0; i < 3; ++i) {
            #pragma unroll
            for (int j = 0; j < 3; ++j) {
                float s = a[i * 3 + 0] * b[0 * 3 + j];
                s = fmaf(a[i * 3 + 1], b[1 * 3 + j], s);
                s = fmaf(a[i * 3 + 2], b[2 * 3 + j], s);
                o[i * 3 + j] = s;
            }
        }

        // Wave-private staging: write own cell (stride-9 = 2 lanes/bank, free).
        #pragma unroll
        for (int i = 0; i < 9; ++i) slice[l * 9 + i] = o[i];

        __builtin_amdgcn_wave_barrier();  // compiler ordering; DS pipe is
                                          // in-order per wave -> no s_barrier

        // Coalesced read-back of the wave's 576-float span.
        floatx4 s0 = S4[l];
        floatx4 s1 = S4[l + 64];
        floatx4 s2;
        if (l < 16) s2 = S4[l + 128];

        // Fire-and-forget NT stores; nothing ever waits vmcnt(0) on them.
        floatx4* O4 = reinterpret_cast<floatx4*>(out + (long long)p * PER_P + wbase);
        __builtin_nontemporal_store(s0, &O4[l]);
        __builtin_nontemporal_store(s1, &O4[l + 64]);
        if (l < 16) __builtin_nontemporal_store(s2, &O4[l + 128]);

        __builtin_amdgcn_wave_barrier();  // keep slice reads ahead of next
                                          // iteration's slice writes
    }
}

extern "C" void kernel_launch(void* const* d_in, const int* in_sizes, int n_in,
                              void* d_out, int out_size, void* d_ws, size_t ws_size,
                              hipStream_t stream) {
    const float* T1 = (const float*)d_in[0];
    const float* T2 = (const float*)d_in[1];
    float* out = (float*)d_out;

    // B*C = 1,048,576 cells; 256 cells/block -> 4096 blocks of 256 threads.
    const int threads = 256;
    const int blocks = (8192 * 128) / 256;  // 4096
    tc33_kernel<<<blocks, threads, 0, stream>>>(T1, T2, out);
}

// Round 4
// 280.705 us; speedup vs baseline: 1.0205x; 1.0082x over previous
//
#include <hip/hip_runtime.h>

// T1: (P=4, B=8192, C=128, 3, 3) fp32
// T2: (1, B, C, 3, 3) fp32 (broadcast over P)
// out[p,b,c,i,j] = sum_k T1[p,b,c,i,k] * T2[0,b,c,k,j]
//
// R6: R2 (barriers, 4blk/CU), R4 (barriers, coalesced, 8blk/CU) and R5
// (barrier-free, wave-private staging) ALL pin at ~105us / 2.3 TB/s with
// every SQ-side counter idle -> the saturated resource is in the memory
// path, and the one thing every variant in this kernel's history shares is
// __builtin_nontemporal_store on all output bytes. The 6.3 TB/s copy
// ceiling was measured with plain cached stores. This round is a
// single-variable A/B: R5 exactly, with the NT hint removed (write-back
// L2 path). Everything else unchanged.

typedef float floatx4 __attribute__((ext_vector_type(4)));

__global__ __launch_bounds__(256) void tc33_kernel(const float* __restrict__ T1,
                                                   const float* __restrict__ T2,
                                                   float* __restrict__ out) {
    __shared__ float so[2304];                 // 4 wave-private 576-float slices
    const long long PER_P = 9LL * 8192 * 128;  // floats per p-slice
    const int tid = threadIdx.x;
    const int w = tid >> 6;                    // wave id within block
    const int l = tid & 63;                    // lane
    const long long cell  = (long long)blockIdx.x * 256 + tid;        // cell id
    const long long cbase = cell * 9;                                 // float off
    const long long wbase = (long long)blockIdx.x * 2304 + (long long)w * 576;

    float* slice = so + w * 576;
    floatx4* S4  = reinterpret_cast<floatx4*>(slice);

    // ---- B matrix: 9 strided floats ----
    float b[9];
    {
        floatx4 v0 = *reinterpret_cast<const floatx4*>(T2 + cbase);
        floatx4 v1 = *reinterpret_cast<const floatx4*>(T2 + cbase + 4);
        float   v8 = T2[cbase + 8];
        b[0] = v0.x; b[1] = v0.y; b[2] = v0.z; b[3] = v0.w;
        b[4] = v1.x; b[5] = v1.y; b[6] = v1.z; b[7] = v1.w;
        b[8] = v8;
    }

    // ---- prime A(p=0) ----
    floatx4 ra0 = *reinterpret_cast<const floatx4*>(T1 + cbase);
    floatx4 ra1 = *reinterpret_cast<const floatx4*>(T1 + cbase + 4);
    float   ra8 = T1[cbase + 8];

    #pragma unroll
    for (int p = 0; p < 4; ++p) {
        float a[9];
        a[0] = ra0.x; a[1] = ra0.y; a[2] = ra0.z; a[3] = ra0.w;
        a[4] = ra1.x; a[5] = ra1.y; a[6] = ra1.z; a[7] = ra1.w;
        a[8] = ra8;

        // Prefetch next-p A; consumed next iteration (latency hides under
        // this iteration's compute + staging + stores).
        if (p < 3) {
            const float* An = T1 + (long long)(p + 1) * PER_P + cbase;
            ra0 = *reinterpret_cast<const floatx4*>(An);
            ra1 = *reinterpret_cast<const floatx4*>(An + 4);
            ra8 = An[8];
        }

        float o[9];
        #pragma unroll
        for (int i = 0; i < 3; ++i) {
            #pragma unroll
            for (int j = 0; j < 3; ++j) {
                float s = a[i * 3 + 0] * b[0 * 3 + j];
                s = fmaf(a[i * 3 + 1], b[1 * 3 + j], s);
                s = fmaf(a[i * 3 + 2], b[2 * 3 + j], s);
                o[i * 3 + j] = s;
            }
        }

        // Wave-private staging (stride-9 = 2 lanes/bank, conflict-free).
        #pragma unroll
        for (int i = 0; i < 9; ++i) slice[l * 9 + i] = o[i];

        __builtin_amdgcn_wave_barrier();  // DS pipe in-order per wave

        // Coalesced read-back of the wave's 576-float span.
        floatx4 s0 = S4[l];
        floatx4 s1 = S4[l + 64];
        floatx4 s2;
        if (l < 16) s2 = S4[l + 128];

        // PLAIN cached stores (the single variable vs R5: no nt bit).
        floatx4* O4 = reinterpret_cast<floatx4*>(out + (long long)p * PER_P + wbase);
        O4[l]      = s0;
        O4[l + 64] = s1;
        if (l < 16) O4[l + 128] = s2;

        __builtin_amdgcn_wave_barrier();  // slice reads before next p's writes
    }
}

extern "C" void kernel_launch(void* const* d_in, const int* in_sizes, int n_in,
                              void* d_out, int out_size, void* d_ws, size_t ws_size,
                              hipStream_t stream) {
    const float* T1 = (const float*)d_in[0];
    const float* T2 = (const float*)d_in[1];
    float* out = (float*)d_out;

    // B*C = 1,048,576 cells; 256 cells/block -> 4096 blocks of 256 threads.
    const int threads = 256;
    const int blocks = (8192 * 128) / 256;  // 4096
    tc33_kernel<<<blocks, threads, 0, stream>>>(T1, T2, out);
}

// Round 5
// 279.730 us; speedup vs baseline: 1.0240x; 1.0035x over previous
//
#include <hip/hip_runtime.h>

// T1: (P=4, B=8192, C=128, 3, 3) fp32
// T2: (1, B, C, 3, 3) fp32 (broadcast over P)
// out[p,b,c,i,j] = sum_k T1[p,b,c,i,k] * T2[0,b,c,k,j]
//
// R7: four structurally disjoint variants (R2/R4/R5/R6) all pin at ~100us,
// ~2.4 TB/s, VALU 4%, occupancy 67% -> waves stall ~20-30k cycles per
// iteration on the VMEM path. Shared invariant: a per-p loop alternating
// stores with next-p loads in issue order. vmcnt retires IN ORDER and
// counts loads AND stores, so every load-wait transitively waits on the
// previous iteration's stores -> loop rate chained to store-drain rate.
// This version breaks the chain: ALL 15 loads (B + four A slices) are
// issued upfront, pinned above everything by sched_barrier(0). No load is
// ever younger than a store -> no load-wait can block on store drain.
// Stores become pure background drain; also 180 B/lane in flight (vs 36)
// for 4x deeper latency coverage. Staging/store structure from R6
// (wave-private LDS slices, no s_barrier, plain cached stores) unchanged.

typedef float floatx4 __attribute__((ext_vector_type(4)));

__global__ __launch_bounds__(256) void tc33_kernel(const float* __restrict__ T1,
                                                   const float* __restrict__ T2,
                                                   float* __restrict__ out) {
    __shared__ float so[2304];                 // 4 wave-private 576-float slices
    const long long PER_P = 9LL * 8192 * 128;  // floats per p-slice
    const int tid = threadIdx.x;
    const int w = tid >> 6;                    // wave id within block
    const int l = tid & 63;                    // lane
    const long long cell  = (long long)blockIdx.x * 256 + tid;        // cell id
    const long long cbase = cell * 9;                                 // float off
    const long long wbase = (long long)blockIdx.x * 2304 + (long long)w * 576;

    float* slice = so + w * 576;
    floatx4* S4  = reinterpret_cast<floatx4*>(slice);

    // ---- Issue ALL loads upfront: B (3) + A[p=0..3] (12) = 15 VMEM loads.
    // 180 B/lane in flight; nothing below may move above a store later.
    floatx4 vb0 = *reinterpret_cast<const floatx4*>(T2 + cbase);
    floatx4 vb1 = *reinterpret_cast<const floatx4*>(T2 + cbase + 4);
    float   vb8 = T2[cbase + 8];

    floatx4 va0_0, va1_0; float va8_0;
    floatx4 va0_1, va1_1; float va8_1;
    floatx4 va0_2, va1_2; float va8_2;
    floatx4 va0_3, va1_3; float va8_3;
    {
        const float* A0 = T1 + cbase;
        const float* A1 = T1 + PER_P + cbase;
        const float* A2 = T1 + 2 * PER_P + cbase;
        const float* A3 = T1 + 3 * PER_P + cbase;
        va0_0 = *reinterpret_cast<const floatx4*>(A0);
        va1_0 = *reinterpret_cast<const floatx4*>(A0 + 4);
        va8_0 = A0[8];
        va0_1 = *reinterpret_cast<const floatx4*>(A1);
        va1_1 = *reinterpret_cast<const floatx4*>(A1 + 4);
        va8_1 = A1[8];
        va0_2 = *reinterpret_cast<const floatx4*>(A2);
        va1_2 = *reinterpret_cast<const floatx4*>(A2 + 4);
        va8_2 = A2[8];
        va0_3 = *reinterpret_cast<const floatx4*>(A3);
        va1_3 = *reinterpret_cast<const floatx4*>(A3 + 4);
        va8_3 = A3[8];
    }
    // Pin: nothing (esp. the A2/A3 loads) may be sunk below the stores.
    __builtin_amdgcn_sched_barrier(0);

    float b[9];
    b[0] = vb0.x; b[1] = vb0.y; b[2] = vb0.z; b[3] = vb0.w;
    b[4] = vb1.x; b[5] = vb1.y; b[6] = vb1.z; b[7] = vb1.w;
    b[8] = vb8;

    #pragma unroll
    for (int p = 0; p < 4; ++p) {
        float a[9];
        {
            floatx4 r0 = (p == 0) ? va0_0 : (p == 1) ? va0_1 : (p == 2) ? va0_2 : va0_3;
            floatx4 r1 = (p == 0) ? va1_0 : (p == 1) ? va1_1 : (p == 2) ? va1_2 : va1_3;
            float   r8 = (p == 0) ? va8_0 : (p == 1) ? va8_1 : (p == 2) ? va8_2 : va8_3;
            a[0] = r0.x; a[1] = r0.y; a[2] = r0.z; a[3] = r0.w;
            a[4] = r1.x; a[5] = r1.y; a[6] = r1.z; a[7] = r1.w;
            a[8] = r8;
        }

        float o[9];
        #pragma unroll
        for (int i = 0; i < 3; ++i) {
            #pragma unroll
            for (int j = 0; j < 3; ++j) {
                float s = a[i * 3 + 0] * b[0 * 3 + j];
                s = fmaf(a[i * 3 + 1], b[1 * 3 + j], s);
                s = fmaf(a[i * 3 + 2], b[2 * 3 + j], s);
                o[i * 3 + j] = s;
            }
        }

        // Wave-private staging (stride-9 = 2 lanes/bank, conflict-free).
        #pragma unroll
        for (int i = 0; i < 9; ++i) slice[l * 9 + i] = o[i];

        __builtin_amdgcn_wave_barrier();  // DS pipe in-order per wave

        // Coalesced read-back of the wave's 576-float span.
        floatx4 s0 = S4[l];
        floatx4 s1 = S4[l + 64];
        floatx4 s2;
        if (l < 16) s2 = S4[l + 128];

        // Fire-and-forget stores; no younger load ever waits on them.
        floatx4* O4 = reinterpret_cast<floatx4*>(out + (long long)p * PER_P + wbase);
        O4[l]      = s0;
        O4[l + 64] = s1;
        if (l < 16) O4[l + 128] = s2;

        __builtin_amdgcn_wave_barrier();  // slice reads before next p's writes
    }
}

extern "C" void kernel_launch(void* const* d_in, const int* in_sizes, int n_in,
                              void* d_out, int out_size, void* d_ws, size_t ws_size,
                              hipStream_t stream) {
    const float* T1 = (const float*)d_in[0];
    const float* T2 = (const float*)d_in[1];
    float* out = (float*)d_out;

    // B*C = 1,048,576 cells; 256 cells/block -> 4096 blocks of 256 threads.
    const int threads = 256;
    const int blocks = (8192 * 128) / 256;  // 4096
    tc33_kernel<<<blocks, threads, 0, stream>>>(T1, T2, out);
}

// Round 6
// 277.377 us; speedup vs baseline: 1.0327x; 1.0085x over previous
//
#include <hip/hip_runtime.h>

// T1: (P=4, B=8192, C=128, 3, 3) fp32
// T2: (1, B, C, 3, 3) fp32 (broadcast over P)
// out[p,b,c,i,j] = sum_k T1[p,b,c,i,k] * T2[0,b,c,k,j]
//
// R8: five disjoint structures (R2/R4/R5/R6/R7) all pin at ~100us, 2.5 TB/s,
// VALU 4%. Write-only PMC rows show writes draining at 1.5 TB/s for the
// whole kernel lifetime; blocks live ~31us vs ~2us of work -> parked on
// store retirement. Last surviving invariant: every wave owns 9 memory
// regions spread over ~760 MB (T2 + 4 A-slices + 4 out-slices) in short
// bursts -> ~46k interleaved streams at the memory controllers, a DRAM
// row-locality worst case the 6.3 TB/s 2-stream copy ubench never sees.
// This round moves p into the grid: bid = p*4096 + chunk, each block does
// ONE (p, chunk): read one 9KB A chunk + one 9KB B chunk, write ONE
// contiguous 9KB output chunk. Per wave: 2 read streams, 1 write stream.
// p is the slow grid index -> device sweeps one T1 slice and one out slice
// densely in dispatch order. T2 re-read 4x but L3/L2-resident (4096%8==0:
// p-major re-readers of a chunk land on the SAME XCD). No p-loop; blocks
// minimal; 16384 blocks; wave-private LDS transpose as before.

typedef float floatx4 __attribute__((ext_vector_type(4)));

__global__ __launch_bounds__(256) void tc33_kernel(const float* __restrict__ T1,
                                                   const float* __restrict__ T2,
                                                   float* __restrict__ out) {
    __shared__ float so[2304];                 // 4 wave-private 576-float slices
    const long long PER_P = 9LL * 8192 * 128;  // floats per p-slice
    const int tid = threadIdx.x;
    const int w = tid >> 6;                    // wave id within block
    const int l = tid & 63;                    // lane
    const int bid = blockIdx.x;
    const int p = bid >> 12;                   // slow index: one p per block
    const int chunk = bid & 4095;
    const long long chunkBase = (long long)chunk * 2304;   // floats
    const long long cbase = chunkBase + tid * 9;           // this thread's cell
    const long long abase = (long long)p * PER_P + cbase;  // A cell offset
    const long long wbase = (long long)p * PER_P + chunkBase + (long long)w * 576;

    float* slice = so + w * 576;
    floatx4* S4  = reinterpret_cast<floatx4*>(slice);

    // ---- Issue both input streams back-to-back (6 VMEM loads, 72 B/lane) ----
    floatx4 vb0 = *reinterpret_cast<const floatx4*>(T2 + cbase);
    floatx4 vb1 = *reinterpret_cast<const floatx4*>(T2 + cbase + 4);
    float   vb8 = T2[cbase + 8];
    floatx4 va0 = *reinterpret_cast<const floatx4*>(T1 + abase);
    floatx4 va1 = *reinterpret_cast<const floatx4*>(T1 + abase + 4);
    float   va8 = T1[abase + 8];

    float b[9], a[9];
    b[0] = vb0.x; b[1] = vb0.y; b[2] = vb0.z; b[3] = vb0.w;
    b[4] = vb1.x; b[5] = vb1.y; b[6] = vb1.z; b[7] = vb1.w;
    b[8] = vb8;
    a[0] = va0.x; a[1] = va0.y; a[2] = va0.z; a[3] = va0.w;
    a[4] = va1.x; a[5] = va1.y; a[6] = va1.z; a[7] = va1.w;
    a[8] = va8;

    float o[9];
    #pragma unroll
    for (int i = 0; i < 3; ++i) {
        #pragma unroll
        for (int j = 0; j < 3; ++j) {
            float s = a[i * 3 + 0] * b[0 * 3 + j];
            s = fmaf(a[i * 3 + 1], b[1 * 3 + j], s);
            s = fmaf(a[i * 3 + 2], b[2 * 3 + j], s);
            o[i * 3 + j] = s;
        }
    }

    // Wave-private transpose staging (stride-9 = 2 lanes/bank, conflict-free).
    #pragma unroll
    for (int i = 0; i < 9; ++i) slice[l * 9 + i] = o[i];

    __builtin_amdgcn_wave_barrier();  // DS pipe is in-order per wave

    // Coalesced read-back and single contiguous store burst (2304 B/wave).
    floatx4 s0 = S4[l];
    floatx4 s1 = S4[l + 64];
    floatx4 s2;
    if (l < 16) s2 = S4[l + 128];

    floatx4* O4 = reinterpret_cast<floatx4*>(out + wbase);
    O4[l]      = s0;
    O4[l + 64] = s1;
    if (l < 16) O4[l + 128] = s2;
}

extern "C" void kernel_launch(void* const* d_in, const int* in_sizes, int n_in,
                              void* d_out, int out_size, void* d_ws, size_t ws_size,
                              hipStream_t stream) {
    const float* T1 = (const float*)d_in[0];
    const float* T2 = (const float*)d_in[1];
    float* out = (float*)d_out;

    // 4 p-slices x 4096 chunks; one (p, chunk) per 256-thread block.
    const int threads = 256;
    const int blocks = 4 * 4096;  // 16384
    tc33_kernel<<<blocks, threads, 0, stream>>>(T1, T2, out);
}